// Round 5
// baseline (139.684 us; speedup 1.0000x reference)
//
#include <hip/hip_runtime.h>
#include <hip/hip_bf16.h>
#include <stdint.h>

// B=8, T=1024, D=U=640, H=10, d=64
#define B_DIM 8
#define T_DIM 1024
#define D_DIM 640
#define H_DIM 10
#define LOG2E 1.442695041f

typedef unsigned short ushort_t;
typedef __attribute__((ext_vector_type(8))) short short8;
typedef __attribute__((ext_vector_type(4))) float f32x4;

__device__ __forceinline__ ushort_t f32_to_bf16(float f) {
    unsigned int u = __builtin_bit_cast(unsigned int, f);
    u += 0x7fffu + ((u >> 16) & 1u);   // RNE
    return (ushort_t)(u >> 16);
}
__device__ __forceinline__ float v_exp2(float x) {
    float r; asm("v_exp_f32 %0, %1" : "=v"(r) : "v"(x)); return r;
}
__device__ __forceinline__ unsigned cvt_pk_bf16(float a, float b) {
    unsigned r; asm("v_cvt_pk_bf16_f32 %0, %1, %2" : "=v"(r) : "v"(a), "v"(b)); return r;
}

// async global->LDS. HW dest = wave-uniform base + lane*size (linear).
__device__ __forceinline__ void gload16(const void* g, void* l) {
    auto gp = reinterpret_cast<const __attribute__((address_space(1))) uint32_t*>(
        reinterpret_cast<uintptr_t>(g));
    auto lp = reinterpret_cast<__attribute__((address_space(3))) uint32_t*>(
        reinterpret_cast<uintptr_t>(l));
    __builtin_amdgcn_global_load_lds(gp, lp, 16, 0, 0);
}
__device__ __forceinline__ void gload4(const void* g, void* l) {
    auto gp = reinterpret_cast<const __attribute__((address_space(1))) uint32_t*>(
        reinterpret_cast<uintptr_t>(g));
    auto lp = reinterpret_cast<__attribute__((address_space(3))) uint32_t*>(
        reinterpret_cast<uintptr_t>(l));
    __builtin_amdgcn_global_load_lds(gp, lp, 4, 0, 0);
}

// split-K chunk tables: 23 chunks per (b,h); (q-block, first tile, #tiles)
__constant__ int CH_BX[23] = {0,0,0,0, 1, 2,2, 3,3, 4,4,4, 5,5,5, 6,6,6,6, 7,7,7,7};
__constant__ int CH_K0[23] = {0,4,8,12, 0, 0,4, 0,4, 0,4,8, 0,4,8, 0,4,8,12, 0,4,8,12};
__constant__ int CH_NT[23] = {4,4,4,4, 4, 4,2, 4,4, 4,4,2, 4,4,4, 4,4,4,2, 4,4,4,4};

// ---------------------------------------------------------------------------
// Kernel A: fused { W transpose->bf16 (blocks 0..299) , x->bf16 (blocks 300+) }
// ---------------------------------------------------------------------------
__global__ __launch_bounds__(256) void convwt(
    const float* __restrict__ x,
    const float* __restrict__ Wq, const float* __restrict__ Wk, const float* __restrict__ Wv,
    ushort_t* __restrict__ xb, ushort_t* __restrict__ Wt)
{
    const int tid = threadIdx.x;
    if (blockIdx.x < 300) {
        const int w = blockIdx.x / 100, rem = blockIdx.x % 100;
        const int k0 = (rem % 10) * 64, n0 = (rem / 10) * 64;
        const float* W = (w == 0) ? Wq : (w == 1) ? Wk : Wv;
        ushort_t* Wo = Wt + (size_t)w * D_DIM * D_DIM;

        __shared__ alignas(16) ushort_t st[64][72];
        const int r = tid >> 2, cs = (tid & 3) * 16;
        #pragma unroll
        for (int j = 0; j < 4; ++j) {
            float4 v = *reinterpret_cast<const float4*>(
                &W[(size_t)(k0 + r) * D_DIM + n0 + cs + j * 4]);
            st[r][cs + j * 4 + 0] = f32_to_bf16(v.x);
            st[r][cs + j * 4 + 1] = f32_to_bf16(v.y);
            st[r][cs + j * 4 + 2] = f32_to_bf16(v.z);
            st[r][cs + j * 4 + 3] = f32_to_bf16(v.w);
        }
        __syncthreads();
        const int nr = tid >> 2, ks = (tid & 3) * 16;
        ushort_t tmp[16];
        #pragma unroll
        for (int j = 0; j < 16; ++j) tmp[j] = st[ks + j][nr];
        ushort_t* dst = &Wo[(size_t)(n0 + nr) * D_DIM + k0 + ks];
        *reinterpret_cast<short8*>(dst)     = *reinterpret_cast<const short8*>(&tmp[0]);
        *reinterpret_cast<short8*>(dst + 8) = *reinterpret_cast<const short8*>(&tmp[8]);
    } else {
        const int n8 = (B_DIM * T_DIM * D_DIM) / 8;
        for (int i = (blockIdx.x - 300) * 256 + tid; i < n8; i += 2048 * 256) {
            float4 a = *reinterpret_cast<const float4*>(&x[i * 8]);
            float4 b = *reinterpret_cast<const float4*>(&x[i * 8 + 4]);
            ushort_t o[8] = {f32_to_bf16(a.x), f32_to_bf16(a.y), f32_to_bf16(a.z), f32_to_bf16(a.w),
                             f32_to_bf16(b.x), f32_to_bf16(b.y), f32_to_bf16(b.z), f32_to_bf16(b.w)};
            *reinterpret_cast<short8*>(&xb[i * 8]) = *reinterpret_cast<const short8*>(o);
        }
    }
}

// ---------------------------------------------------------------------------
// Kernel B: bf16 MFMA GEMM (XCD-remapped flat grid of 960). Q,K row-major;
// V written per-head transposed Vt[((b*10+h)*64+d)*1024 + t].
// ---------------------------------------------------------------------------
__global__ __launch_bounds__(256) void gemm_qkv(
    const ushort_t* __restrict__ xb, const ushort_t* __restrict__ Wt,
    ushort_t* __restrict__ Qb, ushort_t* __restrict__ Kb, ushort_t* __restrict__ Vt)
{
    // same-m-panel blocks share an XCD: xcd gets m-panels xcd*8..xcd*8+7
    const int L = blockIdx.x;
    const int xcd = L & 7, j = L >> 3;
    const int m0 = (xcd * 8 + (j & 7)) * 128;
    const int nz = j >> 3;               // 0..14
    const int n0 = (nz % 5) * 128;
    const int w  = nz / 5;

    const ushort_t* Wm = Wt + (size_t)w * D_DIM * D_DIM;

    __shared__ alignas(16) ushort_t As[128 * 64];
    __shared__ alignas(16) ushort_t Bs[128 * 64];

    const int tid = threadIdx.x;
    const int lane = tid & 63, wave = tid >> 6;
    const int lo = lane & 15, g = lane >> 4;
    const int wm = wave >> 1, wn = wave & 1;
    const int srow = tid >> 3, schunk = tid & 7;

    f32x4 acc[4][4];
    #pragma unroll
    for (int i = 0; i < 4; ++i)
        #pragma unroll
        for (int jj = 0; jj < 4; ++jj) acc[i][jj] = (f32x4){0.f, 0.f, 0.f, 0.f};

    for (int k0 = 0; k0 < D_DIM; k0 += 64) {
        #pragma unroll
        for (int i = 0; i < 4; ++i) {
            int row = i * 32 + srow;
            int sc = schunk ^ (row & 7);
            gload16(&xb[(size_t)(m0 + row) * D_DIM + k0 + sc * 8], &As[i * 2048 + tid * 8]);
            gload16(&Wm[(size_t)(n0 + row) * D_DIM + k0 + sc * 8], &Bs[i * 2048 + tid * 8]);
        }
        __syncthreads();
        #pragma unroll
        for (int ks = 0; ks < 2; ++ks) {
            short8 af[4], bf[4];
            #pragma unroll
            for (int t = 0; t < 4; ++t) {
                int arow = wm * 64 + t * 16 + lo;
                int ach = (ks * 4 + g) ^ (arow & 7);
                af[t] = *reinterpret_cast<const short8*>(&As[arow * 64 + ach * 8]);
                int brow = wn * 64 + t * 16 + lo;
                int bch = (ks * 4 + g) ^ (brow & 7);
                bf[t] = *reinterpret_cast<const short8*>(&Bs[brow * 64 + bch * 8]);
            }
            __builtin_amdgcn_s_setprio(1);
            #pragma unroll
            for (int mi = 0; mi < 4; ++mi)
                #pragma unroll
                for (int ni = 0; ni < 4; ++ni)
                    acc[mi][ni] = __builtin_amdgcn_mfma_f32_16x16x32_bf16(
                        af[mi], bf[ni], acc[mi][ni], 0, 0, 0);
            __builtin_amdgcn_s_setprio(0);
        }
        __syncthreads();
    }

    if (w == 2) {
        #pragma unroll
        for (int mi = 0; mi < 4; ++mi)
            #pragma unroll
            for (int ni = 0; ni < 4; ++ni) {
                int row = m0 + wm * 64 + mi * 16 + g * 4;   // 4 consecutive tokens
                int col = n0 + wn * 64 + ni * 16 + lo;
                int bb = row >> 10, tt = row & 1023;
                int hh = col >> 6, dd = col & 63;
                ushort_t pk[4];
                #pragma unroll
                for (int r = 0; r < 4; ++r) pk[r] = f32_to_bf16(acc[mi][ni][r]);
                ushort4 o = make_ushort4(pk[0], pk[1], pk[2], pk[3]);
                *reinterpret_cast<ushort4*>(
                    &Vt[((size_t)(bb * H_DIM + hh) * 64 + dd) * T_DIM + tt]) = o;
            }
    } else {
        ushort_t* Y = (w == 0) ? Qb : Kb;
        #pragma unroll
        for (int mi = 0; mi < 4; ++mi)
            #pragma unroll
            for (int ni = 0; ni < 4; ++ni)
                #pragma unroll
                for (int r = 0; r < 4; ++r) {
                    int row = m0 + wm * 64 + mi * 16 + g * 4 + r;
                    int col = n0 + wn * 64 + ni * 16 + lo;
                    Y[(size_t)row * D_DIM + col] = f32_to_bf16(acc[mi][ni][r]);
                }
    }
}

// ---------------------------------------------------------------------------
// Kernel D: masks + zero-init of out accumulator and l accumulator.
// qs = sign(sum|Q_h|)*mask (f32), km16 = sign(sum|K_h|) bf16.
// ---------------------------------------------------------------------------
__global__ __launch_bounds__(256) void masks_kernel(
    const ushort_t* __restrict__ Qb, const ushort_t* __restrict__ Kb,
    const int* __restrict__ msk, float* __restrict__ qs, ushort_t* __restrict__ km16,
    float* __restrict__ outZ, float* __restrict__ laccZ)
{
    const int gidx = blockIdx.x * 256 + threadIdx.x;   // 655360 threads
    // zero d_out (5,242,880 f32 = 655360 * 8)
    const float4 z4 = make_float4(0.f, 0.f, 0.f, 0.f);
    reinterpret_cast<float4*>(outZ)[gidx * 2]     = z4;
    reinterpret_cast<float4*>(outZ)[gidx * 2 + 1] = z4;
    // zero lacc (81,920 f32 = 20480 float4)
    if (gidx < 20480) reinterpret_cast<float4*>(laccZ)[gidx] = z4;

    const int rowid = blockIdx.x * 32 + (threadIdx.x >> 3);   // h*8192 + b*1024 + t
    const int p = threadIdx.x & 7;
    const int h = rowid >> 13;
    const int rem = rowid & 8191;
    const ushort_t* qrow = &Qb[(size_t)rem * D_DIM + h * 64 + p * 8];
    const ushort_t* krow = &Kb[(size_t)rem * D_DIM + h * 64 + p * 8];
    unsigned int oq = 0, ok = 0;
    #pragma unroll
    for (int j = 0; j < 8; ++j) {
        oq |= (unsigned int)(qrow[j] & 0x7fff);
        ok |= (unsigned int)(krow[j] & 0x7fff);
    }
    #pragma unroll
    for (int m = 1; m < 8; m <<= 1) {
        oq |= (unsigned int)__shfl_xor((int)oq, m);
        ok |= (unsigned int)__shfl_xor((int)ok, m);
    }
    if (p == 0) {
        qs[rowid] = (oq != 0 ? 1.f : 0.f) * (float)msk[rem];
        km16[rowid] = (ok != 0) ? (ushort_t)0x3F80 : (ushort_t)0;
    }
}

// ---------------------------------------------------------------------------
// Kernel D2: per-row shift M: 16 if any unpadded key strictly before row,
// else -9984. One wave per (h,b); exclusive prefix-OR via ballot.
// ---------------------------------------------------------------------------
__global__ __launch_bounds__(64) void prefix_kernel(const ushort_t* __restrict__ km16,
                                                    float* __restrict__ Mv)
{
    const int hb = blockIdx.x;
    const int lane = threadIdx.x;
    const ushort_t* kr = &km16[(size_t)hb * T_DIM];
    float* mv = &Mv[(size_t)hb * T_DIM];
    bool running = false;
    for (int c = 0; c < 16; ++c) {
        ushort_t v = kr[c * 64 + lane];
        unsigned long long bal = __ballot(v != 0);
        unsigned long long pre = bal & ((1ull << lane) - 1ull);
        bool any = running || (pre != 0ull);
        mv[c * 64 + lane] = any ? 16.f : -9984.f;
        running = running || (bal != 0ull);
    }
}

// ---------------------------------------------------------------------------
// Kernel E: split-K flash attention. Work unit = (b,h, q-block128, k-chunk<=4).
// Fixed-shift softmax makes partial (O,l) exactly addable -> atomic merge.
// 1840 uniform blocks; O accumulated straight into d_out (f32 atomics).
// ---------------------------------------------------------------------------
__global__ __launch_bounds__(256, 3) void attn_split(
    const ushort_t* __restrict__ Qb, const ushort_t* __restrict__ Kb,
    const ushort_t* __restrict__ Vt, const ushort_t* __restrict__ km16,
    const float* __restrict__ Mv, float* __restrict__ outAcc,
    float* __restrict__ lacc_g)
{
    // chunk mapping: same-(b,h) chunks share an XCD
    const int bid = blockIdx.x;              // 0..1839
    const int xcd = bid & 7, idx = bid >> 3; // idx 0..229
    const int gq = idx % 10, c = idx / 10;   // c 0..22
    const int g8 = xcd + 8 * gq;             // (b,h) group 0..79
    const int b = g8 & 7, h = g8 >> 3;
    const int bx = CH_BX[c];
    const int kt0 = CH_K0[c];
    const int nt = CH_NT[c];
    const int q0 = bx * 128;

    __shared__ alignas(16) ushort_t QP[128 * 64];   // Q tile, then P (wave-private rows)
    __shared__ alignas(16) ushort_t KT[2][64 * 64];
    __shared__ alignas(16) ushort_t VT[2][64 * 64];
    __shared__ alignas(16) ushort_t KM[1024];       // bf16 key mask
    __shared__ alignas(16) float QM[128];           // per-row shift M

    const int tid = threadIdx.x;
    const int lane = tid & 63, wave = tid >> 6;
    const int lo = lane & 15, g = lane >> 4;
    const int srow = tid >> 3, schunk = tid & 7;

    const size_t rowbase = (size_t)b * T_DIM;
    const int colbase = h * 64;
    const int hb = h * B_DIM + b;
    const size_t vtbase = (size_t)(b * H_DIM + h) * 64;

#define STAGE_KV(t, buf) do {                                                        \
        int _k0 = (t) * 64;                                                          \
        _Pragma("unroll")                                                            \
        for (int _i = 0; _i < 2; ++_i) {                                             \
            int _rr = _i * 32 + srow;                                                \
            int _sc = schunk ^ (_rr & 7);                                            \
            gload16(&Kb[(rowbase + _k0 + _rr) * D_DIM + colbase + _sc * 8],          \
                    &KT[buf][_i * 2048 + tid * 8]);                                  \
            gload16(&Vt[(vtbase + _rr) * T_DIM + _k0 + _sc * 8],                     \
                    &VT[buf][_i * 2048 + tid * 8]);                                  \
        }                                                                            \
    } while (0)

    // ---- prologue staging (per wave: Q=4, KM=2, QM=1, KV0=4) ----
    #pragma unroll
    for (int i = 0; i < 4; ++i) {
        int row = i * 32 + srow;
        int sc = schunk ^ (row & 7);
        gload16(&Qb[(rowbase + q0 + row) * D_DIM + colbase + sc * 8], &QP[i * 2048 + tid * 8]);
    }
    #pragma unroll
    for (int i = 0; i < 2; ++i)
        gload4(&km16[(size_t)hb * T_DIM + wave * 256 + i * 128 + lane * 2],
               &KM[wave * 256 + i * 128]);
    if (lane < 32)
        gload4(&Mv[(size_t)hb * T_DIM + q0 + wave * 32 + lane], &QM[wave * 32]);
    STAGE_KV(kt0, 0);
    asm volatile("s_waitcnt vmcnt(4)" ::: "memory");   // drain Q/KM/QM; keep KV0
    __builtin_amdgcn_s_barrier();

    // Q fragments + per-row exp2-domain constants
    short8 qf[2][2];
    float cAr[2][4], cBr[2][4];
    #pragma unroll
    for (int ms = 0; ms < 2; ++ms) {
        #pragma unroll
        for (int ks = 0; ks < 2; ++ks) {
            int row = wave * 32 + ms * 16 + lo;
            int ch = (ks * 4 + g) ^ (row & 7);
            qf[ms][ks] = *reinterpret_cast<const short8*>(&QP[row * 64 + ch * 8]);
        }
        #pragma unroll
        for (int r = 0; r < 4; ++r) {
            float M = QM[wave * 32 + ms * 16 + g * 4 + r];
            cAr[ms][r] = -M * LOG2E;                       // allowed
            cBr[ms][r] = cAr[ms][r] - 10000.0f * LOG2E;    // directional-masked
        }
    }
    const float S2 = 0.125f * LOG2E;

    float lacc[2][4] = {{0.f}};
    f32x4 of[2][4];
    #pragma unroll
    for (int ms = 0; ms < 2; ++ms)
        #pragma unroll
        for (int df = 0; df < 4; ++df) of[ms][df] = (f32x4){0.f, 0.f, 0.f, 0.f};

    for (int kt = kt0; kt < kt0 + nt; ++kt) {
        const int cur = (kt - kt0) & 1;
        const int k0 = kt * 64;

        if (kt + 1 < kt0 + nt) {
            STAGE_KV(kt + 1, cur ^ 1);
            asm volatile("s_waitcnt vmcnt(4)" ::: "memory");
        } else {
            asm volatile("s_waitcnt vmcnt(0)" ::: "memory");
        }
        __builtin_amdgcn_s_barrier();

        ushort_t kmu[4];
        #pragma unroll
        for (int nf = 0; nf < 4; ++nf) kmu[nf] = KM[k0 + nf * 16 + lo];

        // S = Q K^T
        short8 kf[4][2];
        #pragma unroll
        for (int nf = 0; nf < 4; ++nf)
            #pragma unroll
            for (int ks = 0; ks < 2; ++ks) {
                int row = nf * 16 + lo;
                int ch = (ks * 4 + g) ^ (row & 7);
                kf[nf][ks] = *reinterpret_cast<const short8*>(&KT[cur][row * 64 + ch * 8]);
            }
        f32x4 sf[2][4];
        __builtin_amdgcn_s_setprio(1);
        #pragma unroll
        for (int ms = 0; ms < 2; ++ms)
            #pragma unroll
            for (int nf = 0; nf < 4; ++nf) {
                f32x4 z = (f32x4){0.f, 0.f, 0.f, 0.f};
                z = __builtin_amdgcn_mfma_f32_16x16x32_bf16(qf[ms][0], kf[nf][0], z, 0, 0, 0);
                z = __builtin_amdgcn_mfma_f32_16x16x32_bf16(qf[ms][1], kf[nf][1], z, 0, 0, 0);
                sf[ms][nf] = z;
            }
        __builtin_amdgcn_s_setprio(0);

        // fixed-shift softmax in exp2 domain; P (bf16) into QP (wave-private rows)
        #pragma unroll
        for (int ms = 0; ms < 2; ++ms)
            #pragma unroll
            for (int r = 0; r < 4; ++r) {
                const int rowl = wave * 32 + ms * 16 + g * 4 + r;
                const int trow = q0 + rowl;
                float p[4];
                #pragma unroll
                for (int nf = 0; nf < 4; ++nf) {
                    int kcol = k0 + nf * 16 + lo;
                    float cc = (kcol >= trow) ? cBr[ms][r] : cAr[ms][r];
                    cc = (kmu[nf] != 0) ? cc : -1e30f;     // key padding dominates
                    p[nf] = v_exp2(fmaf(sf[ms][nf][r], S2, cc));
                }
                lacc[ms][r] += (p[0] + p[1]) + (p[2] + p[3]);
                unsigned pk01 = cvt_pk_bf16(p[0], p[1]);
                unsigned pk23 = cvt_pk_bf16(p[2], p[3]);
                const int base = rowl * 64, sw = (rowl & 7);
                int c0 = lo,      h0 = ((c0 >> 3) ^ sw);
                int c1 = 16 + lo, h1 = ((c1 >> 3) ^ sw);
                int c2 = 32 + lo, h2 = ((c2 >> 3) ^ sw);
                int c3 = 48 + lo, h3 = ((c3 >> 3) ^ sw);
                QP[base + h0 * 8 + (c0 & 7)] = (ushort_t)pk01;
                QP[base + h1 * 8 + (c1 & 7)] = (ushort_t)(pk01 >> 16);
                QP[base + h2 * 8 + (c2 & 7)] = (ushort_t)pk23;
                QP[base + h3 * 8 + (c3 & 7)] = (ushort_t)(pk23 >> 16);
            }
        asm volatile("s_waitcnt lgkmcnt(0)" ::: "memory");
        __builtin_amdgcn_sched_barrier(0);

        // O += P V   (P rows wave-private -> no barrier needed)
        #pragma unroll
        for (int ks = 0; ks < 2; ++ks) {
            short8 pf[2], vf[4];
            #pragma unroll
            for (int ms = 0; ms < 2; ++ms) {
                int row = wave * 32 + ms * 16 + lo;
                int ch = (ks * 4 + g) ^ (row & 7);
                pf[ms] = *reinterpret_cast<const short8*>(&QP[row * 64 + ch * 8]);
            }
            #pragma unroll
            for (int df = 0; df < 4; ++df) {
                int row = df * 16 + lo;
                int ch = (ks * 4 + g) ^ (row & 7);
                vf[df] = *reinterpret_cast<const short8*>(&VT[cur][row * 64 + ch * 8]);
            }
            __builtin_amdgcn_s_setprio(1);
            #pragma unroll
            for (int ms = 0; ms < 2; ++ms)
                #pragma unroll
                for (int df = 0; df < 4; ++df)
                    of[ms][df] = __builtin_amdgcn_mfma_f32_16x16x32_bf16(
                        pf[ms], vf[df], of[ms][df], 0, 0, 0);
            __builtin_amdgcn_s_setprio(0);
        }
        __builtin_amdgcn_s_barrier();   // all reads of buf[cur] done
    }

    // epilogue: atomically merge partial (O, l)
    #pragma unroll
    for (int ms = 0; ms < 2; ++ms)
        #pragma unroll
        for (int r = 0; r < 4; ++r) {
            float l = lacc[ms][r];
            l += __shfl_xor(l, 1); l += __shfl_xor(l, 2);
            l += __shfl_xor(l, 4); l += __shfl_xor(l, 8);
            const int trow = q0 + wave * 32 + ms * 16 + g * 4 + r;
            if (lo == 0)
                unsafeAtomicAdd(&lacc_g[(size_t)hb * T_DIM + trow], l);
            #pragma unroll
            for (int df = 0; df < 4; ++df)
                unsafeAtomicAdd(&outAcc[(rowbase + trow) * D_DIM + colbase + df * 16 + lo],
                                of[ms][df][r]);
        }
#undef STAGE_KV
}

// ---------------------------------------------------------------------------
// Kernel F: finalize — out *= qs / l (in place).
// ---------------------------------------------------------------------------
__global__ __launch_bounds__(256) void finalize(float* __restrict__ out,
                                                const float* __restrict__ lacc_g,
                                                const float* __restrict__ qs)
{
    const int idx = blockIdx.x * 256 + threadIdx.x;   // per float4, 1,310,720 total
    const int row = idx / 160;                        // [b*1024 + t]
    const int c4 = idx % 160;
    const int b = row >> 10, t = row & 1023;
    const int h = c4 >> 4;
    const size_t mrow = (size_t)h * 8192 + b * 1024 + t;  // == (h*8+b)*1024 + t
    const float sc = qs[mrow] / lacc_g[mrow];
    float4 v = reinterpret_cast<float4*>(out)[idx];
    v.x *= sc; v.y *= sc; v.z *= sc; v.w *= sc;
    reinterpret_cast<float4*>(out)[idx] = v;
}

// ---------------------------------------------------------------------------
extern "C" void kernel_launch(void* const* d_in, const int* in_sizes, int n_in,
                              void* d_out, int out_size, void* d_ws, size_t ws_size,
                              hipStream_t stream)
{
    const float* x   = (const float*)d_in[0];
    const int*   msk = (const int*)d_in[1];
    const float* Wq  = (const float*)d_in[2];
    const float* Wk  = (const float*)d_in[3];
    const float* Wv  = (const float*)d_in[4];
    float* out = (float*)d_out;

    // workspace layout (bytes)
    char* ws = (char*)d_ws;
    ushort_t* xb = (ushort_t*)(ws);                    // 10,485,760
    ushort_t* Wt = (ushort_t*)(ws + 10485760);         //  2,457,600
    ushort_t* Qb = (ushort_t*)(ws + 12943360);         // 10,485,760
    ushort_t* Kb = (ushort_t*)(ws + 23429120);         // 10,485,760
    ushort_t* Vt = (ushort_t*)(ws + 33914880);         // 10,485,760
    float*    qs = (float*)(ws + 44400640);            //    327,680
    ushort_t* km = (ushort_t*)(ws + 44728320);         //    163,840
    float*    Mv = (float*)(ws + 44892160);            //    327,680
    float*    lg = (float*)(ws + 45219840);            //    327,680
    if (ws_size < 45547520) return;

    convwt<<<2348, 256, 0, stream>>>(x, Wq, Wk, Wv, xb, Wt);
    gemm_qkv<<<960, 256, 0, stream>>>(xb, Wt, Qb, Kb, Vt);
    masks_kernel<<<2560, 256, 0, stream>>>(Qb, Kb, msk, qs, km, out, lg);
    prefix_kernel<<<80, 64, 0, stream>>>(km, Mv);
    attn_split<<<1840, 256, 0, stream>>>(Qb, Kb, Vt, km, Mv, out, lg);
    finalize<<<5120, 256, 0, stream>>>(out, lg, qs);
}